// Round 5
// baseline (408.056 us; speedup 1.0000x reference)
//
#include <hip/hip_runtime.h>
#include <hip/hip_bf16.h>
#include <stdint.h>

// B=8, N=2048, E=1024, H=16, D=64 -> M = B*N = 16384.
// qkv row layout per token: [3][H=16][D=64] = 3072 elems (6144 B)

typedef __attribute__((ext_vector_type(8))) short short8;
typedef __attribute__((ext_vector_type(8))) unsigned short ushort8;
typedef __attribute__((ext_vector_type(16))) float floatx16;

__device__ __forceinline__ unsigned short f2bf(float f) {
  union { float f; uint32_t u; } x; x.f = f;
  uint32_t u = x.u;
  return (unsigned short)((u + 0x7fffu + ((u >> 16) & 1u)) >> 16);  // RNE
}
__device__ __forceinline__ float bf2f(unsigned short s) {
  union { uint32_t u; float f; } x; x.u = ((uint32_t)s) << 16; return x.f;
}
__device__ __forceinline__ void unpack8(uint4 u, float* f) {
  f[0] = bf2f((unsigned short)(u.x & 0xffffu)); f[1] = bf2f((unsigned short)(u.x >> 16));
  f[2] = bf2f((unsigned short)(u.y & 0xffffu)); f[3] = bf2f((unsigned short)(u.y >> 16));
  f[4] = bf2f((unsigned short)(u.z & 0xffffu)); f[5] = bf2f((unsigned short)(u.z >> 16));
  f[6] = bf2f((unsigned short)(u.w & 0xffffu)); f[7] = bf2f((unsigned short)(u.w >> 16));
}

// ---------------- fused fp32 -> bf16 cast ----------------
// 8-elem groups: x 2,097,152 | Wqkv 393,216 | Wo 131,072 -> 2,621,440 total
__global__ __launch_bounds__(256) void cvt_all(const float* __restrict__ x,
                                               const float* __restrict__ w1,
                                               const float* __restrict__ w2,
                                               unsigned short* __restrict__ xb,
                                               unsigned short* __restrict__ w1b,
                                               unsigned short* __restrict__ w2b) {
  int i = blockIdx.x * 256 + threadIdx.x;
  const float* src;
  unsigned short* dst;
  if (i < 2097152) {
    src = x; dst = xb;
  } else if (i < 2097152 + 393216) {
    i -= 2097152; src = w1; dst = w1b;
  } else {
    i -= 2490368; src = w2; dst = w2b;
  }
  long base = (long)i * 8;
  const float4* p = (const float4*)(src + base);
  float4 a = p[0], b = p[1];
  ushort8 r;
  r[0] = f2bf(a.x); r[1] = f2bf(a.y); r[2] = f2bf(a.z); r[3] = f2bf(a.w);
  r[4] = f2bf(b.x); r[5] = f2bf(b.y); r[6] = f2bf(b.z); r[7] = f2bf(b.w);
  *(ushort8*)(dst + base) = r;
}

// ---------------- async global->LDS, 16B per lane ----------------
__device__ __forceinline__ void gl2lds16(const void* g, void* l) {
  __builtin_amdgcn_global_load_lds(
      (const uint32_t __attribute__((address_space(1)))*)g,
      (uint32_t __attribute__((address_space(3)))*)(uint32_t)(uintptr_t)l,
      16, 0, 0);
}

// ---------------- bf16 GEMM (r2-measured config): C = A*B^T + bias ----------------
// 128x128 tile, BK=64, 4 waves of 64x64 = 2x2 mfma_f32_32x32x16_bf16.
// XOR-swizzled LDS: chunk L = r*8 + (c ^ (r&7)).
// Writes C at column offset colOff with row stride ldc (for N-sliced dispatches).
template <bool OUT_BF16>
__device__ __forceinline__ void gemm_core(const unsigned short* __restrict__ A,
                                          const unsigned short* __restrict__ Bm,
                                          const float* __restrict__ bias,
                                          void* __restrict__ Cout, int K,
                                          int colOff, int ldc) {
  __shared__ __align__(16) unsigned short lA[128 * 64];
  __shared__ __align__(16) unsigned short lB[128 * 64];
  const int tid = threadIdx.x;
  const int lane = tid & 63;
  const int wave = tid >> 6;
  const long row0 = (long)blockIdx.y * 128;
  const long col0 = (long)blockIdx.x * 128;
  const int wr = (wave & 1) * 64;
  const int wc = (wave >> 1) * 64;
  const int l32 = lane & 31;
  const int lhi = lane >> 5;
  const int l7 = lane & 7;

  floatx16 acc[2][2] = {};

  const int rstage = tid >> 3;
  const int cstage = (tid & 7) ^ (rstage & 7);
  const unsigned short* gA0 = A + (row0 + rstage) * (long)K + cstage * 8;
  const unsigned short* gB0 = Bm + (col0 + rstage) * (long)K + cstage * 8;
  char* ldsA0 = (char*)lA + tid * 16;
  char* ldsB0 = (char*)lB + tid * 16;
  const long rowstep = (long)32 * K;

  int aRow[2], bRow[2], sOff[4];
#pragma unroll
  for (int i = 0; i < 2; i++) aRow[i] = (wr + i * 32 + l32) * 128;
#pragma unroll
  for (int j = 0; j < 2; j++) bRow[j] = (wc + j * 32 + l32) * 128;
#pragma unroll
  for (int s = 0; s < 4; s++) sOff[s] = ((2 * s + lhi) ^ l7) * 16;

  for (int k0 = 0; k0 < K; k0 += 64) {
    __syncthreads();
#pragma unroll
    for (int p = 0; p < 4; p++) {
      gl2lds16(gA0 + p * rowstep + k0, ldsA0 + p * 4096);
      gl2lds16(gB0 + p * rowstep + k0, ldsB0 + p * 4096);
    }
    __syncthreads();

#pragma unroll
    for (int s = 0; s < 4; s++) {
      short8 a0 = *(const short8*)((char*)lA + aRow[0] + sOff[s]);
      short8 a1 = *(const short8*)((char*)lA + aRow[1] + sOff[s]);
      short8 b0 = *(const short8*)((char*)lB + bRow[0] + sOff[s]);
      short8 b1 = *(const short8*)((char*)lB + bRow[1] + sOff[s]);
      acc[0][0] = __builtin_amdgcn_mfma_f32_32x32x16_bf16(a0, b0, acc[0][0], 0, 0, 0);
      acc[0][1] = __builtin_amdgcn_mfma_f32_32x32x16_bf16(a0, b1, acc[0][1], 0, 0, 0);
      acc[1][0] = __builtin_amdgcn_mfma_f32_32x32x16_bf16(a1, b0, acc[1][0], 0, 0, 0);
      acc[1][1] = __builtin_amdgcn_mfma_f32_32x32x16_bf16(a1, b1, acc[1][1], 0, 0, 0);
    }
  }

  float bv[2];
#pragma unroll
  for (int j = 0; j < 2; j++) bv[j] = bias[col0 + wc + j * 32 + l32];

#pragma unroll
  for (int i = 0; i < 2; i++) {
#pragma unroll
    for (int j = 0; j < 2; j++) {
      const long col = colOff + col0 + wc + j * 32 + l32;
      const long rbase = row0 + wr + i * 32 + 4 * lhi;
#pragma unroll
      for (int reg = 0; reg < 16; reg++) {
        const long row = rbase + (reg & 3) + 8 * (reg >> 2);
        float v = acc[i][j][reg] + bv[j];
        if (OUT_BF16)
          ((unsigned short*)Cout)[row * ldc + col] = f2bf(v);
        else
          ((float*)Cout)[row * ldc + col] = v;
      }
    }
  }
}

__global__ __launch_bounds__(256) void gemm_q(const unsigned short* __restrict__ A,
                                              const unsigned short* __restrict__ Bm,
                                              const float* __restrict__ bias,
                                              unsigned short* __restrict__ Cout, int K) {
  gemm_core<true>(A, Bm, bias, Cout, K, 0, 3072);
}
__global__ __launch_bounds__(256) void gemm_k(const unsigned short* __restrict__ A,
                                              const unsigned short* __restrict__ Bm,
                                              const float* __restrict__ bias,
                                              unsigned short* __restrict__ Cout, int K) {
  gemm_core<true>(A, Bm, bias, Cout, K, 1024, 3072);
}
__global__ __launch_bounds__(256) void gemm_v(const unsigned short* __restrict__ A,
                                              const unsigned short* __restrict__ Bm,
                                              const float* __restrict__ bias,
                                              unsigned short* __restrict__ Cout, int K) {
  gemm_core<true>(A, Bm, bias, Cout, K, 2048, 3072);
}
__global__ __launch_bounds__(256) void gemm_out(const unsigned short* __restrict__ A,
                                                const unsigned short* __restrict__ Bm,
                                                const float* __restrict__ bias,
                                                float* __restrict__ Cout, int K) {
  gemm_core<false>(A, Bm, bias, Cout, K, 0, 1024);
}

// ---------------- per-token cross-head attention v3: LDS broadcast ----------------
// One wave per token (4 tokens/block). Stage the token's 6144 B of qkv into LDS
// with 6 global_load_lds insts, then compute with broadcast ds_reads.
// lane = head*4 + sub; sub owns d-range [sub*16, sub*16+16).
// energy[j] = sum_d Q[head][d]*K[j][d] / 32 (shfl_xor over 4 sub-lanes);
// softmax over j (head axis); o[d] = sum_j p[j]*V[j][d].
// Raw-reshape scramble: row = b*2048 + head*128 + s/16, col = (s%16)*64 + d.
__global__ __launch_bounds__(256) void attn_kernel(const unsigned short* __restrict__ qkv,
                                                   unsigned short* __restrict__ out2) {
  __shared__ __align__(16) char lds[4 * 6144];  // 24 KB
  const int tid = threadIdx.x;
  const int wave = tid >> 6;
  const int lane = tid & 63;
  const int token = blockIdx.x * 4 + wave;
  const int head = lane >> 2;
  const int sub = lane & 3;
  const int b = token >> 11;
  const int s = token & 2047;

  const char* gbase = (const char*)qkv + (long)token * 6144;
  char* lbase = lds + wave * 6144;
#pragma unroll
  for (int p = 0; p < 6; p++)
    gl2lds16(gbase + p * 1024 + lane * 16, lbase + p * 1024 + lane * 16);
  __syncthreads();

  // q sub-range: 16 elems (broadcast across the 16 heads' identical sub lanes is free)
  float qf[16];
  {
    const uint4* qp = (const uint4*)(lbase + head * 128 + sub * 32);
    unpack8(qp[0], qf);
    unpack8(qp[1], qf + 8);
  }

  float e[16];
  const char* kbase = lbase + 2048 + sub * 32;
  for (int j = 0; j < 16; j++) {
    const uint4* kp = (const uint4*)(kbase + j * 128);
    float kf[16];
    unpack8(kp[0], kf);
    unpack8(kp[1], kf + 8);
    float a0 = 0.f, a1 = 0.f, a2 = 0.f, a3 = 0.f;
#pragma unroll
    for (int c = 0; c < 4; c++) {
      a0 += qf[c] * kf[c];
      a1 += qf[c + 4] * kf[c + 4];
      a2 += qf[c + 8] * kf[c + 8];
      a3 += qf[c + 12] * kf[c + 12];
    }
    float ej = (a0 + a1) + (a2 + a3);
    ej += __shfl_xor(ej, 1);
    ej += __shfl_xor(ej, 2);
    e[j] = ej * 0.03125f;  // / sqrt(1024)
  }

  float mx = e[0];
#pragma unroll
  for (int j = 1; j < 16; j++) mx = fmaxf(mx, e[j]);
  float sum = 0.f;
#pragma unroll
  for (int j = 0; j < 16; j++) { e[j] = __expf(e[j] - mx); sum += e[j]; }
  const float inv = 1.f / sum;

  float o[16];
#pragma unroll
  for (int d = 0; d < 16; d++) o[d] = 0.f;
  const char* vbase = lbase + 4096 + sub * 32;
  for (int j = 0; j < 16; j++) {
    const float wgt = e[j] * inv;
    const uint4* vp = (const uint4*)(vbase + j * 128);
    float vf[16];
    unpack8(vp[0], vf);
    unpack8(vp[1], vf + 8);
#pragma unroll
    for (int d = 0; d < 16; d++) o[d] += wgt * vf[d];
  }

  const long row = (long)b * 2048 + head * 128 + (s >> 4);
  unsigned short* op = out2 + row * 1024 + (long)(s & 15) * 64 + sub * 16;
#pragma unroll
  for (int w = 0; w < 2; w++) {
    ushort8 r;
#pragma unroll
    for (int c = 0; c < 8; c++) r[c] = f2bf(o[w * 8 + c]);
    *(ushort8*)(op + w * 8) = r;
  }
}

extern "C" void kernel_launch(void* const* d_in, const int* in_sizes, int n_in,
                              void* d_out, int out_size, void* d_ws, size_t ws_size,
                              hipStream_t stream) {
  const float* x    = (const float*)d_in[0];  // [8,2048,1024]
  const float* Wqkv = (const float*)d_in[1];  // [3072,1024]
  const float* bqkv = (const float*)d_in[2];  // [3072]
  const float* Wo   = (const float*)d_in[3];  // [1024,1024]
  const float* bo   = (const float*)d_in[4];  // [1024]
  float* out = (float*)d_out;                 // [8,2048,1024] fp32

  char* ws = (char*)d_ws;
  unsigned short* x_bf    = (unsigned short*)(ws);              // 32 MB
  unsigned short* wqkv_bf = (unsigned short*)(ws + 33554432);   // 6 MB
  unsigned short* wo_bf   = (unsigned short*)(ws + 39845888);   // 2 MB
  unsigned short* qkv_bf  = (unsigned short*)(ws + 41943040);   // 96 MB
  unsigned short* out2_bf = (unsigned short*)(ws + 142606336);  // 32 MB

  cvt_all<<<10240, 256, 0, stream>>>(x, Wqkv, Wo, x_bf, wqkv_bf, wo_bf);

  // qkv = x @ Wqkv^T + bqkv, split into 3 N=1024 dispatches (visibility + L2-resident B)
  dim3 gp(1024 / 128, 16384 / 128);
  gemm_q<<<gp, 256, 0, stream>>>(x_bf, wqkv_bf,               bqkv,        qkv_bf, 1024);
  gemm_k<<<gp, 256, 0, stream>>>(x_bf, wqkv_bf + 1024 * 1024, bqkv + 1024, qkv_bf, 1024);
  gemm_v<<<gp, 256, 0, stream>>>(x_bf, wqkv_bf + 2048 * 1024, bqkv + 2048, qkv_bf, 1024);

  // one wave per token: 16384 tokens / 4 waves per block
  attn_kernel<<<4096, 256, 0, stream>>>(qkv_bf, out2_bf);

  dim3 g2(1024 / 128, 16384 / 128);
  gemm_out<<<g2, 256, 0, stream>>>(out2_bf, wo_bf, bo, out, 1024);
}

// Round 6
// 337.977 us; speedup vs baseline: 1.2073x; 1.2073x over previous
//
#include <hip/hip_runtime.h>
#include <hip/hip_bf16.h>
#include <stdint.h>

// B=8, N=2048, E=1024, H=16, D=64 -> M = B*N = 16384.
// qkv row layout per token: [3][H=16][D=64] = 3072 elems (6144 B)

typedef __attribute__((ext_vector_type(8))) short short8;
typedef __attribute__((ext_vector_type(8))) unsigned short ushort8;
typedef __attribute__((ext_vector_type(16))) float floatx16;

__device__ __forceinline__ unsigned short f2bf(float f) {
  union { float f; uint32_t u; } x; x.f = f;
  uint32_t u = x.u;
  return (unsigned short)((u + 0x7fffu + ((u >> 16) & 1u)) >> 16);  // RNE
}
__device__ __forceinline__ float bf2f(unsigned short s) {
  union { uint32_t u; float f; } x; x.u = ((uint32_t)s) << 16; return x.f;
}
__device__ __forceinline__ void unpack8(uint4 u, float* f) {
  f[0] = bf2f((unsigned short)(u.x & 0xffffu)); f[1] = bf2f((unsigned short)(u.x >> 16));
  f[2] = bf2f((unsigned short)(u.y & 0xffffu)); f[3] = bf2f((unsigned short)(u.y >> 16));
  f[4] = bf2f((unsigned short)(u.z & 0xffffu)); f[5] = bf2f((unsigned short)(u.z >> 16));
  f[6] = bf2f((unsigned short)(u.w & 0xffffu)); f[7] = bf2f((unsigned short)(u.w >> 16));
}

// ---------------- fused fp32 -> bf16 cast ----------------
// 8-elem groups: x 2,097,152 | Wqkv 393,216 | Wo 131,072 -> 2,621,440 total
__global__ __launch_bounds__(256) void cvt_all(const float* __restrict__ x,
                                               const float* __restrict__ w1,
                                               const float* __restrict__ w2,
                                               unsigned short* __restrict__ xb,
                                               unsigned short* __restrict__ w1b,
                                               unsigned short* __restrict__ w2b) {
  int i = blockIdx.x * 256 + threadIdx.x;
  const float* src;
  unsigned short* dst;
  if (i < 2097152) {
    src = x; dst = xb;
  } else if (i < 2097152 + 393216) {
    i -= 2097152; src = w1; dst = w1b;
  } else {
    i -= 2490368; src = w2; dst = w2b;
  }
  long base = (long)i * 8;
  const float4* p = (const float4*)(src + base);
  float4 a = p[0], b = p[1];
  ushort8 r;
  r[0] = f2bf(a.x); r[1] = f2bf(a.y); r[2] = f2bf(a.z); r[3] = f2bf(a.w);
  r[4] = f2bf(b.x); r[5] = f2bf(b.y); r[6] = f2bf(b.z); r[7] = f2bf(b.w);
  *(ushort8*)(dst + base) = r;
}

// ---------------- async global->LDS, 16B per lane ----------------
__device__ __forceinline__ void gl2lds16(const void* g, void* l) {
  __builtin_amdgcn_global_load_lds(
      (const uint32_t __attribute__((address_space(1)))*)g,
      (uint32_t __attribute__((address_space(3)))*)(uint32_t)(uintptr_t)l,
      16, 0, 0);
}

// ---------------- bf16 GEMM: C = A*B^T + bias ----------------
// 128x128 tile, BK=64, 4 waves of 64x64 = 2x2 mfma_f32_32x32x16_bf16.
// XOR-swizzled LDS: chunk L = r*8 + (c ^ (r&7)).
// 1D grid with group-of-8-rows block swizzle: XCD = id%8 = row offset within
// group, so each XCD re-reads ONE 256KB A panel per group (not all of A) and
// iterates columns against an L2-resident B. Fixes the 4x A over-fetch seen in
// r5 (FETCH 133 MB vs 34 ideal when XCD == column).
template <bool OUT_BF16>
__device__ __forceinline__ void gemm_core(const unsigned short* __restrict__ A,
                                          const unsigned short* __restrict__ Bm,
                                          const float* __restrict__ bias,
                                          void* __restrict__ Cout, int K,
                                          int ncols, int ldc) {
  const int id = blockIdx.x;
  const int local = id % (8 * ncols);
  const int brow = (id / (8 * ncols)) * 8 + (local & 7);
  const int bcol = local >> 3;

  __shared__ __align__(16) unsigned short lA[128 * 64];
  __shared__ __align__(16) unsigned short lB[128 * 64];
  const int tid = threadIdx.x;
  const int lane = tid & 63;
  const int wave = tid >> 6;
  const long row0 = (long)brow * 128;
  const long col0 = (long)bcol * 128;
  const int wr = (wave & 1) * 64;
  const int wc = (wave >> 1) * 64;
  const int l32 = lane & 31;
  const int lhi = lane >> 5;
  const int l7 = lane & 7;

  floatx16 acc[2][2] = {};

  const int rstage = tid >> 3;
  const int cstage = (tid & 7) ^ (rstage & 7);
  const unsigned short* gA0 = A + (row0 + rstage) * (long)K + cstage * 8;
  const unsigned short* gB0 = Bm + (col0 + rstage) * (long)K + cstage * 8;
  char* ldsA0 = (char*)lA + tid * 16;
  char* ldsB0 = (char*)lB + tid * 16;
  const long rowstep = (long)32 * K;

  int aRow[2], bRow[2], sOff[4];
#pragma unroll
  for (int i = 0; i < 2; i++) aRow[i] = (wr + i * 32 + l32) * 128;
#pragma unroll
  for (int j = 0; j < 2; j++) bRow[j] = (wc + j * 32 + l32) * 128;
#pragma unroll
  for (int s = 0; s < 4; s++) sOff[s] = ((2 * s + lhi) ^ l7) * 16;

  for (int k0 = 0; k0 < K; k0 += 64) {
    __syncthreads();
#pragma unroll
    for (int p = 0; p < 4; p++) {
      gl2lds16(gA0 + p * rowstep + k0, ldsA0 + p * 4096);
      gl2lds16(gB0 + p * rowstep + k0, ldsB0 + p * 4096);
    }
    __syncthreads();

#pragma unroll
    for (int s = 0; s < 4; s++) {
      short8 a0 = *(const short8*)((char*)lA + aRow[0] + sOff[s]);
      short8 a1 = *(const short8*)((char*)lA + aRow[1] + sOff[s]);
      short8 b0 = *(const short8*)((char*)lB + bRow[0] + sOff[s]);
      short8 b1 = *(const short8*)((char*)lB + bRow[1] + sOff[s]);
      acc[0][0] = __builtin_amdgcn_mfma_f32_32x32x16_bf16(a0, b0, acc[0][0], 0, 0, 0);
      acc[0][1] = __builtin_amdgcn_mfma_f32_32x32x16_bf16(a0, b1, acc[0][1], 0, 0, 0);
      acc[1][0] = __builtin_amdgcn_mfma_f32_32x32x16_bf16(a1, b0, acc[1][0], 0, 0, 0);
      acc[1][1] = __builtin_amdgcn_mfma_f32_32x32x16_bf16(a1, b1, acc[1][1], 0, 0, 0);
    }
  }

  float bv[2];
#pragma unroll
  for (int j = 0; j < 2; j++) bv[j] = bias[col0 + wc + j * 32 + l32];

#pragma unroll
  for (int i = 0; i < 2; i++) {
#pragma unroll
    for (int j = 0; j < 2; j++) {
      const long col = col0 + wc + j * 32 + l32;
      const long rbase = row0 + wr + i * 32 + 4 * lhi;
#pragma unroll
      for (int reg = 0; reg < 16; reg++) {
        const long row = rbase + (reg & 3) + 8 * (reg >> 2);
        float v = acc[i][j][reg] + bv[j];
        if (OUT_BF16)
          ((unsigned short*)Cout)[row * ldc + col] = f2bf(v);
        else
          ((float*)Cout)[row * ldc + col] = v;
      }
    }
  }
}

__global__ __launch_bounds__(256) void gemm_qkv(const unsigned short* __restrict__ A,
                                                const unsigned short* __restrict__ Bm,
                                                const float* __restrict__ bias,
                                                unsigned short* __restrict__ Cout, int K) {
  gemm_core<true>(A, Bm, bias, Cout, K, 24, 3072);
}
__global__ __launch_bounds__(256) void gemm_out(const unsigned short* __restrict__ A,
                                                const unsigned short* __restrict__ Bm,
                                                const float* __restrict__ bias,
                                                float* __restrict__ Cout, int K) {
  gemm_core<false>(A, Bm, bias, Cout, K, 8, 1024);
}

// ---------------- per-token cross-head attention v3: LDS broadcast ----------------
// One wave per token (4 tokens/block). Stage the token's 6144 B of qkv into LDS
// with 6 global_load_lds insts, then compute with broadcast ds_reads.
// lane = head*4 + sub; sub owns d-range [sub*16, sub*16+16).
// energy[j] = sum_d Q[head][d]*K[j][d] / 32 (shfl_xor over 4 sub-lanes);
// softmax over j (head axis); o[d] = sum_j p[j]*V[j][d].
// Raw-reshape scramble: row = b*2048 + head*128 + s/16, col = (s%16)*64 + d.
__global__ __launch_bounds__(256) void attn_kernel(const unsigned short* __restrict__ qkv,
                                                   unsigned short* __restrict__ out2) {
  __shared__ __align__(16) char lds[4 * 6144];  // 24 KB
  const int tid = threadIdx.x;
  const int wave = tid >> 6;
  const int lane = tid & 63;
  const int token = blockIdx.x * 4 + wave;
  const int head = lane >> 2;
  const int sub = lane & 3;
  const int b = token >> 11;
  const int s = token & 2047;

  const char* gbase = (const char*)qkv + (long)token * 6144;
  char* lbase = lds + wave * 6144;
#pragma unroll
  for (int p = 0; p < 6; p++)
    gl2lds16(gbase + p * 1024 + lane * 16, lbase + p * 1024 + lane * 16);
  __syncthreads();

  float qf[16];
  {
    const uint4* qp = (const uint4*)(lbase + head * 128 + sub * 32);
    unpack8(qp[0], qf);
    unpack8(qp[1], qf + 8);
  }

  float e[16];
  const char* kbase = lbase + 2048 + sub * 32;
  for (int j = 0; j < 16; j++) {
    const uint4* kp = (const uint4*)(kbase + j * 128);
    float kf[16];
    unpack8(kp[0], kf);
    unpack8(kp[1], kf + 8);
    float a0 = 0.f, a1 = 0.f, a2 = 0.f, a3 = 0.f;
#pragma unroll
    for (int c = 0; c < 4; c++) {
      a0 += qf[c] * kf[c];
      a1 += qf[c + 4] * kf[c + 4];
      a2 += qf[c + 8] * kf[c + 8];
      a3 += qf[c + 12] * kf[c + 12];
    }
    float ej = (a0 + a1) + (a2 + a3);
    ej += __shfl_xor(ej, 1);
    ej += __shfl_xor(ej, 2);
    e[j] = ej * 0.03125f;  // / sqrt(1024)
  }

  float mx = e[0];
#pragma unroll
  for (int j = 1; j < 16; j++) mx = fmaxf(mx, e[j]);
  float sum = 0.f;
#pragma unroll
  for (int j = 0; j < 16; j++) { e[j] = __expf(e[j] - mx); sum += e[j]; }
  const float inv = 1.f / sum;

  float o[16];
#pragma unroll
  for (int d = 0; d < 16; d++) o[d] = 0.f;
  const char* vbase = lbase + 4096 + sub * 32;
  for (int j = 0; j < 16; j++) {
    const float wgt = e[j] * inv;
    const uint4* vp = (const uint4*)(vbase + j * 128);
    float vf[16];
    unpack8(vp[0], vf);
    unpack8(vp[1], vf + 8);
#pragma unroll
    for (int d = 0; d < 16; d++) o[d] += wgt * vf[d];
  }

  const long row = (long)b * 2048 + head * 128 + (s >> 4);
  unsigned short* op = out2 + row * 1024 + (long)(s & 15) * 64 + sub * 16;
#pragma unroll
  for (int w = 0; w < 2; w++) {
    ushort8 r;
#pragma unroll
    for (int c = 0; c < 8; c++) r[c] = f2bf(o[w * 8 + c]);
    *(ushort8*)(op + w * 8) = r;
  }
}

extern "C" void kernel_launch(void* const* d_in, const int* in_sizes, int n_in,
                              void* d_out, int out_size, void* d_ws, size_t ws_size,
                              hipStream_t stream) {
  const float* x    = (const float*)d_in[0];  // [8,2048,1024]
  const float* Wqkv = (const float*)d_in[1];  // [3072,1024]
  const float* bqkv = (const float*)d_in[2];  // [3072]
  const float* Wo   = (const float*)d_in[3];  // [1024,1024]
  const float* bo   = (const float*)d_in[4];  // [1024]
  float* out = (float*)d_out;                 // [8,2048,1024] fp32

  char* ws = (char*)d_ws;
  unsigned short* x_bf    = (unsigned short*)(ws);              // 32 MB
  unsigned short* wqkv_bf = (unsigned short*)(ws + 33554432);   // 6 MB
  unsigned short* wo_bf   = (unsigned short*)(ws + 39845888);   // 2 MB
  unsigned short* qkv_bf  = (unsigned short*)(ws + 41943040);   // 96 MB
  unsigned short* out2_bf = (unsigned short*)(ws + 142606336);  // 32 MB

  cvt_all<<<10240, 256, 0, stream>>>(x, Wqkv, Wo, x_bf, wqkv_bf, wo_bf);

  // qkv = x @ Wqkv^T + bqkv  (M=16384, N=3072, K=1024), swizzled 1D grid
  gemm_qkv<<<24 * 128, 256, 0, stream>>>(x_bf, wqkv_bf, bqkv, qkv_bf, 1024);

  // one wave per token: 16384 tokens / 4 waves per block
  attn_kernel<<<4096, 256, 0, stream>>>(qkv_bf, out2_bf);

  // out = out2 @ Wo^T + bo  (M=16384, N=1024, K=1024), swizzled 1D grid
  gemm_out<<<8 * 128, 256, 0, stream>>>(out2_bf, wo_bf, bo, out, 1024);
}